// Round 2
// baseline (507.024 us; speedup 1.0000x reference)
//
#include <hip/hip_runtime.h>
#include <math.h>

#define KDIM 4096
#define SPLITS 8
#define PBS_PER_SPLIT 32
#define MAXPB 256

__device__ __forceinline__ void rope_rotate(float& x0, float& x1, int j, int pos) {
    double inv = pow(10000.0, -(double)j / 32.0);
    double ang = (double)pos * inv;
    double cd = cos(ang), sd = sin(ang);
    float c = (float)cd, s = (float)sd;
    float r0 = x0 * c - x1 * s;
    float r1 = x1 * c + x0 * s;
    x0 = r0; x1 = r1;
}

// C[b][n] = dot(A[b,:K=4096], W[n,:K]) for 64 rows, 16 cols per block.
// 4 waves x 4 cols, lane = batch row. LDS-staged chunks, reg-cached A.
template<bool ROPE>
__global__ __launch_bounds__(256) void gemm64(
    const float* __restrict__ A, const float* __restrict__ W,
    float* __restrict__ outq, float* __restrict__ outk, float* __restrict__ outv,
    const int* __restrict__ lens, int N)
{
    __shared__ float sA[64 * 68];
    __shared__ float sW[16 * 68];
    const int tid = threadIdx.x;
    const int n0 = blockIdx.x * 16;
    const int w = tid >> 6;
    const int lane = tid & 63;
    float acc[4] = {0.f, 0.f, 0.f, 0.f};

    for (int kc = 0; kc < KDIM; kc += 64) {
        #pragma unroll
        for (int j = 0; j < 4; ++j) {
            int f4 = tid + j * 256;
            int b = f4 >> 4, kq = f4 & 15;
            float4 v = *(const float4*)&A[(size_t)b * KDIM + kc + kq * 4];
            *(float4*)&sA[b * 68 + kq * 4] = v;
        }
        {
            int r = tid >> 4, kq = tid & 15;
            float4 v = *(const float4*)&W[(size_t)(n0 + r) * KDIM + kc + kq * 4];
            *(float4*)&sW[r * 68 + kq * 4] = v;
        }
        __syncthreads();
        #pragma unroll
        for (int sub = 0; sub < 2; ++sub) {
            float4 areg[8];
            #pragma unroll
            for (int j = 0; j < 8; ++j)
                areg[j] = *(const float4*)&sA[lane * 68 + sub * 32 + j * 4];
            #pragma unroll
            for (int i = 0; i < 4; ++i) {
                const float* wr = &sW[(w * 4 + i) * 68 + sub * 32];
                #pragma unroll
                for (int j = 0; j < 8; ++j) {
                    float4 w4 = *(const float4*)&wr[j * 4];
                    acc[i] += areg[j].x * w4.x + areg[j].y * w4.y
                            + areg[j].z * w4.z + areg[j].w * w4.w;
                }
            }
        }
        __syncthreads();
    }

    const int cbase = n0 + w * 4;
    if (ROPE) {
        const int pos = lens[lane] - 1;
        #pragma unroll
        for (int i = 0; i < 4; i += 2) {
            const int c = cbase + i;
            float x0 = acc[i], x1 = acc[i + 1];
            if (c < 4096) {
                const int d = c & 127;
                if (d < 64) rope_rotate(x0, x1, d >> 1, pos);
                outq[(size_t)lane * 4096 + c]     = x0;
                outq[(size_t)lane * 4096 + c + 1] = x1;
            } else if (c < 4352) {
                const int d = (c - 4096) & 127;
                if (d < 64) rope_rotate(x0, x1, d >> 1, pos);
                outk[lane * 256 + (c - 4096)]     = x0;
                outk[lane * 256 + (c - 4096) + 1] = x1;
            } else {
                outv[lane * 256 + (c - 4352)]     = x0;
                outv[lane * 256 + (c - 4352) + 1] = x1;
            }
        }
    } else {
        *(float4*)&outq[(size_t)lane * N + cbase] =
            make_float4(acc[0], acc[1], acc[2], acc[3]);
    }
}

// Flash-decode partial. Grid: (split, kh, b). Block: 128 threads = 2 waves.
// Each wave: one 16-pos paged block per iter. lane = (g, quad): quad is the
// p-quad in QK and the d-quad (32 dims) in PV. The two waves' partials are
// merged in LDS at the end (they are INDEPENDENT online-softmax states).
__global__ __launch_bounds__(128) void attn_partial(
    const float* __restrict__ qr, const float* __restrict__ knew,
    const float* __restrict__ vnew, const float* __restrict__ kcache,
    const float* __restrict__ vcache, const int* __restrict__ bt,
    const int* __restrict__ lens, float* __restrict__ pO, float* __restrict__ pML)
{
    const int split = blockIdx.x;
    const int kh = blockIdx.y;
    const int b = blockIdx.z;
    const int tid = threadIdx.x;
    const int w = tid >> 6;
    const int lane = tid & 63;
    const int g = lane >> 2;
    const int q4 = lane & 3;

    __shared__ float sQ[16 * 132];
    __shared__ float sK[2][16 * 132];
    __shared__ float sV[2][16 * 132];

    const int len = lens[b];
    #pragma unroll
    for (int j = 0; j < 4; ++j) {
        int f4 = tid + j * 128;
        int gg = f4 >> 5, d4 = f4 & 31;
        *(float4*)&sQ[gg * 132 + d4 * 4] =
            *(const float4*)&qr[((size_t)(b * 32 + kh * 16 + gg)) * 128 + d4 * 4];
    }
    __syncthreads();

    float m = -INFINITY, l = 0.f;
    float4 o4[8];
    #pragma unroll
    for (int r = 0; r < 8; ++r) o4[r] = make_float4(0.f, 0.f, 0.f, 0.f);

    const int pb0 = split * PBS_PER_SPLIT;
    for (int it = 0; it < 16; ++it) {
        const int pb = pb0 + it * 2 + w;
        const int s0 = pb * 16;
        const bool active = (s0 < len);
        if (active) {
            const int blk = bt[b * MAXPB + pb];
            #pragma unroll
            for (int j = 0; j < 8; ++j) {
                int f4 = lane + j * 64;
                int p = f4 >> 5, d4 = f4 & 31;
                int s = s0 + p;
                size_t coff = (((size_t)blk * 16 + p) * 2 + kh) * 128 + d4 * 4;
                size_t noff = ((size_t)(b * 2 + kh)) * 128 + d4 * 4;
                // current token comes from fresh k/v (reference scatters it
                // into the cache; block tables are disjoint per sequence)
                const float4 kv = (s == len - 1) ? *(const float4*)&knew[noff]
                                                 : *(const float4*)&kcache[coff];
                const float4 vv = (s == len - 1) ? *(const float4*)&vnew[noff]
                                                 : *(const float4*)&vcache[coff];
                *(float4*)&sK[w][p * 132 + d4 * 4] = kv;
                *(float4*)&sV[w][p * 132 + d4 * 4] = vv;
            }
        }
        __syncthreads();
        if (active) {
            float sc[4] = {0.f, 0.f, 0.f, 0.f};
            for (int d4 = 0; d4 < 32; ++d4) {
                float4 qv = *(const float4*)&sQ[g * 132 + d4 * 4];
                #pragma unroll
                for (int j = 0; j < 4; ++j) {
                    float4 kv = *(const float4*)&sK[w][(q4 * 4 + j) * 132 + d4 * 4];
                    sc[j] += qv.x * kv.x + qv.y * kv.y + qv.z * kv.z + qv.w * kv.w;
                }
            }
            const float scale = 0.08838834764831845f;
            float tmax = -INFINITY;
            #pragma unroll
            for (int j = 0; j < 4; ++j) {
                int s = s0 + q4 * 4 + j;
                sc[j] = (s < len) ? sc[j] * scale : -INFINITY;
                tmax = fmaxf(tmax, sc[j]);
            }
            tmax = fmaxf(tmax, __shfl_xor(tmax, 1, 4));
            tmax = fmaxf(tmax, __shfl_xor(tmax, 2, 4));
            const float m_new = fmaxf(m, tmax);
            const float corr = expf(m - m_new);  // m=-inf on first tile -> 0
            float pe[4];
            float lsum = 0.f;
            #pragma unroll
            for (int j = 0; j < 4; ++j) { pe[j] = expf(sc[j] - m_new); lsum += pe[j]; }
            lsum += __shfl_xor(lsum, 1, 4);
            lsum += __shfl_xor(lsum, 2, 4);
            l = l * corr + lsum;
            m = m_new;
            #pragma unroll
            for (int r = 0; r < 8; ++r) {
                o4[r].x *= corr; o4[r].y *= corr; o4[r].z *= corr; o4[r].w *= corr;
            }
            #pragma unroll
            for (int pj = 0; pj < 4; ++pj) {
                #pragma unroll
                for (int pq = 0; pq < 4; ++pq) {
                    float pev = __shfl(pe[pj], (lane & ~3) + pq, 64);
                    const float* vr = &sV[w][(pq * 4 + pj) * 132 + q4 * 32];
                    #pragma unroll
                    for (int r = 0; r < 8; ++r) {
                        float4 v4 = *(const float4*)&vr[r * 4];
                        o4[r].x += pev * v4.x; o4[r].y += pev * v4.y;
                        o4[r].z += pev * v4.z; o4[r].w += pev * v4.w;
                    }
                }
            }
        }
        __syncthreads();
    }

    // ---- merge the two waves' independent partials (the round-1 race fix) ----
    // wave 1 publishes its state to LDS (staging buffers are free now)
    if (w == 1) {
        #pragma unroll
        for (int r = 0; r < 8; ++r)
            *(float4*)&sK[1][g * 132 + q4 * 32 + r * 4] = o4[r];
        if (q4 == 0) { sV[1][g * 2] = m; sV[1][g * 2 + 1] = l; }
    }
    __syncthreads();
    if (w == 0) {
        const float m1 = sV[1][g * 2];
        const float l1 = sV[1][g * 2 + 1];
        const float M = fmaxf(m, m1);
        float w0 = 0.f, w1 = 0.f;
        if (M > -INFINITY) {        // guard: both -inf would give exp(nan)
            w0 = expf(m - M);       // m=-inf -> 0
            w1 = expf(m1 - M);
        }
        const float L = l * w0 + l1 * w1;
        size_t base = ((((size_t)(b * 2 + kh)) * SPLITS + split) * 16 + g) * 128 + q4 * 32;
        #pragma unroll
        for (int r = 0; r < 8; ++r) {
            float4 o1 = *(const float4*)&sK[1][g * 132 + q4 * 32 + r * 4];
            float4 ov;
            ov.x = o4[r].x * w0 + o1.x * w1;
            ov.y = o4[r].y * w0 + o1.y * w1;
            ov.z = o4[r].z * w0 + o1.z * w1;
            ov.w = o4[r].w * w0 + o1.w * w1;
            *(float4*)&pO[base + r * 4] = ov;
        }
        if (q4 == 0) {
            size_t mb = ((((size_t)(b * 2 + kh)) * SPLITS + split) * 16 + g) * 2;
            pML[mb] = M;
            pML[mb + 1] = L;
        }
    }
}

__global__ __launch_bounds__(256) void attn_combine(
    const float* __restrict__ pO, const float* __restrict__ pML,
    float* __restrict__ aout)
{
    const int bk = blockIdx.x;      // b*2+kh
    const int tid = threadIdx.x;
    const int g = tid >> 4;
    const int dh = tid & 15;        // d = dh*8 .. dh*8+7

    float ms[SPLITS], ls[SPLITS];
    float M = -INFINITY;
    #pragma unroll
    for (int s = 0; s < SPLITS; ++s) {
        size_t mb = (((size_t)bk * SPLITS + s) * 16 + g) * 2;
        ms[s] = pML[mb]; ls[s] = pML[mb + 1];
        M = fmaxf(M, ms[s]);
    }
    float L = 0.f;
    #pragma unroll
    for (int s = 0; s < SPLITS; ++s) L += ls[s] * expf(ms[s] - M);

    float acc[8] = {0, 0, 0, 0, 0, 0, 0, 0};
    #pragma unroll
    for (int s = 0; s < SPLITS; ++s) {
        float wgt = expf(ms[s] - M);
        const float* src = &pO[(((size_t)bk * SPLITS + s) * 16 + g) * 128 + dh * 8];
        #pragma unroll
        for (int r = 0; r < 8; ++r) acc[r] += wgt * src[r];
    }
    const float invL = 1.f / L;
    const int b = bk >> 1, kh = bk & 1;
    float* dst = &aout[(size_t)b * 4096 + (kh * 16 + g) * 128 + dh * 8];
    #pragma unroll
    for (int r = 0; r < 8; ++r) dst[r] = acc[r] * invL;
}

extern "C" void kernel_launch(void* const* d_in, const int* in_sizes, int n_in,
                              void* d_out, int out_size, void* d_ws, size_t ws_size,
                              hipStream_t stream) {
    const float* hidden = (const float*)d_in[0];
    const float* wqkv   = (const float*)d_in[1];
    const float* wdense = (const float*)d_in[2];
    const float* kcache = (const float*)d_in[3];
    const float* vcache = (const float*)d_in[4];
    const int*   bt     = (const int*)d_in[5];
    const int*   lens   = (const int*)d_in[7];
    float* out = (float*)d_out;

    float* ws     = (float*)d_ws;
    float* q_rope = ws;                 // 64*4096      = 262144
    float* k_new  = ws + 262144;        // 64*2*128     = 16384
    float* v_new  = ws + 278528;        // 16384
    float* pO     = ws + 294912;        // 64*2*8*16*128 = 2097152
    float* pML    = ws + 2392064;       // 64*2*8*16*2  = 32768
    float* aout   = ws + 2424832;       // 262144       (total 10.75 MB)

    gemm64<true><<<dim3(288), dim3(256), 0, stream>>>(
        hidden, wqkv, q_rope, k_new, v_new, lens, 0);
    attn_partial<<<dim3(SPLITS, 2, 64), dim3(128), 0, stream>>>(
        q_rope, k_new, v_new, kcache, vcache, bt, lens, pO, pML);
    attn_combine<<<dim3(128), dim3(256), 0, stream>>>(pO, pML, aout);
    gemm64<false><<<dim3(256), dim3(256), 0, stream>>>(
        aout, wdense, out, nullptr, nullptr, nullptr, 4096);
}

// Round 3
// 471.621 us; speedup vs baseline: 1.0751x; 1.0751x over previous
//
#include <hip/hip_runtime.h>
#include <math.h>

#define KDIM 4096
#define SPLITS 8
#define MAXPB 256
#define NQKV 4608
#define NDENSE 4096
#define KSPLIT 8
#define KRANGE 512

__device__ __forceinline__ void rope_rotate(float& x0, float& x1, int j, int pos) {
    double inv = pow(10000.0, -(double)j / 32.0);
    double ang = (double)pos * inv;
    float c = (float)cos(ang), s = (float)sin(ang);
    float r0 = x0 * c - x1 * s;
    float r1 = x1 * c + x0 * s;
    x0 = r0; x1 = r1;
}

// Split-K GEMM: part[ks][64][N] += A[64][KRANGE slice] * W[N][slice]^T
// Block: 16 cols x 64 rows, 4 waves (wave->4 cols, lane=batch row).
// Reg-prefetch next chunk while computing current (T14).
__global__ __launch_bounds__(256) void gemm_splitk(
    const float* __restrict__ A, const float* __restrict__ W,
    float* __restrict__ part, int N)
{
    __shared__ __align__(16) float sA[64 * 68];
    __shared__ __align__(16) float sW[16 * 68];
    const int tid = threadIdx.x;
    const int n0 = blockIdx.x * 16;
    const int ks = blockIdx.y;
    const int w = tid >> 6;
    const int lane = tid & 63;
    const int kbase0 = ks * KRANGE;
    const int wr = tid >> 4, wkq = tid & 15;

    float acc[4] = {0.f, 0.f, 0.f, 0.f};
    float4 apre[4]; float4 wpre;

    #pragma unroll
    for (int j = 0; j < 4; ++j) {
        int id = tid + j * 256; int bb = id >> 4, kq = id & 15;
        apre[j] = *(const float4*)&A[(size_t)bb * KDIM + kbase0 + kq * 4];
    }
    wpre = *(const float4*)&W[(size_t)(n0 + wr) * KDIM + kbase0 + wkq * 4];
    #pragma unroll
    for (int j = 0; j < 4; ++j) {
        int id = tid + j * 256; int bb = id >> 4, kq = id & 15;
        *(float4*)&sA[bb * 68 + kq * 4] = apre[j];
    }
    *(float4*)&sW[wr * 68 + wkq * 4] = wpre;
    __syncthreads();

    for (int t = 0; t < 8; ++t) {
        if (t + 1 < 8) {
            const int kb = kbase0 + (t + 1) * 64;
            #pragma unroll
            for (int j = 0; j < 4; ++j) {
                int id = tid + j * 256; int bb = id >> 4, kq = id & 15;
                apre[j] = *(const float4*)&A[(size_t)bb * KDIM + kb + kq * 4];
            }
            wpre = *(const float4*)&W[(size_t)(n0 + wr) * KDIM + kb + wkq * 4];
        }
        #pragma unroll
        for (int sub = 0; sub < 2; ++sub) {
            float4 areg[8];
            #pragma unroll
            for (int j = 0; j < 8; ++j)
                areg[j] = *(const float4*)&sA[lane * 68 + sub * 32 + j * 4];
            #pragma unroll
            for (int i = 0; i < 4; ++i) {
                const float* wrow = &sW[(w * 4 + i) * 68 + sub * 32];
                #pragma unroll
                for (int j = 0; j < 8; ++j) {
                    float4 w4 = *(const float4*)&wrow[j * 4];
                    acc[i] += areg[j].x * w4.x + areg[j].y * w4.y
                            + areg[j].z * w4.z + areg[j].w * w4.w;
                }
            }
        }
        __syncthreads();
        if (t + 1 < 8) {
            #pragma unroll
            for (int j = 0; j < 4; ++j) {
                int id = tid + j * 256; int bb = id >> 4, kq = id & 15;
                *(float4*)&sA[bb * 68 + kq * 4] = apre[j];
            }
            *(float4*)&sW[wr * 68 + wkq * 4] = wpre;
            __syncthreads();
        }
    }
    *(float4*)&part[((size_t)ks * 64 + lane) * N + n0 + w * 4] =
        make_float4(acc[0], acc[1], acc[2], acc[3]);
}

// Sum 8 K-partials, apply RoPE, scatter to q_rope / knew / vnew.
__global__ __launch_bounds__(256) void reduce_qkv(
    const float* __restrict__ part, const int* __restrict__ lens,
    float* __restrict__ q_rope, float* __restrict__ knew, float* __restrict__ vnew)
{
    const int b = blockIdx.y;
    const int c0 = (blockIdx.x * 256 + threadIdx.x) * 2;
    float x0 = 0.f, x1 = 0.f;
    #pragma unroll
    for (int ks = 0; ks < KSPLIT; ++ks) {
        float2 v = *(const float2*)&part[((size_t)ks * 64 + b) * NQKV + c0];
        x0 += v.x; x1 += v.y;
    }
    const int pos = lens[b] - 1;
    if (c0 < 4096) {
        const int d = c0 & 127;
        if (d < 64) rope_rotate(x0, x1, d >> 1, pos);
        q_rope[(size_t)b * 4096 + c0] = x0;
        q_rope[(size_t)b * 4096 + c0 + 1] = x1;
    } else if (c0 < 4352) {
        const int kidx = c0 - 4096, kh = kidx >> 7, d = kidx & 127;
        if (d < 64) rope_rotate(x0, x1, d >> 1, pos);
        knew[(b * 2 + kh) * 128 + d] = x0;
        knew[(b * 2 + kh) * 128 + d + 1] = x1;
    } else {
        const int vidx = c0 - 4352, kh = vidx >> 7, d = vidx & 127;
        vnew[(b * 2 + kh) * 128 + d] = x0;
        vnew[(b * 2 + kh) * 128 + d + 1] = x1;
    }
}

// Flash-decode partial. Grid (split, kh, b), block 256 = 4 waves.
// All 4 waves share one 16-pos tile; wave w owns heads w*4..w*4+3.
// QK: lane=(gl, p) -> one 128-dot; softmax via width-16 shfl_xor (in-wave).
// PV: lane=(gl, dq) accumulates O[g][dq*8..+8]; pe via width-16 shfl.
// Striped splits (pb = split + t*8) for load balance; reg-prefetch staging.
__global__ __launch_bounds__(256) void attn_partial(
    const float* __restrict__ qr, const float* __restrict__ knew,
    const float* __restrict__ vnew, const float* __restrict__ kcache,
    const float* __restrict__ vcache, const int* __restrict__ bt,
    const int* __restrict__ lens, float* __restrict__ pO, float* __restrict__ pML)
{
    const int split = blockIdx.x;
    const int kh = blockIdx.y;
    const int b = blockIdx.z;
    const int tid = threadIdx.x;
    const int w = tid >> 6;
    const int lane = tid & 63;
    const int gl = lane >> 4;
    const int sub = lane & 15;
    const int g = w * 4 + gl;

    __shared__ __align__(16) float sQ[16 * 132];
    __shared__ __align__(16) float sK[16 * 132];
    __shared__ __align__(16) float sV[16 * 132];

    const int len = lens[b];
    const int nblk = (len + 15) >> 4;
    const int nt = (nblk - 1 - split) / SPLITS + 1;   // len>=1024 -> split<nblk

    const float scale = 0.08838834764831845f;
    #pragma unroll
    for (int j = 0; j < 2; ++j) {
        int id = tid + j * 256;
        int gg = id >> 5, d4 = id & 31;
        float4 v = *(const float4*)&qr[((size_t)(b * 32 + kh * 16 + gg)) * 128 + d4 * 4];
        v.x *= scale; v.y *= scale; v.z *= scale; v.w *= scale;
        *(float4*)&sQ[gg * 132 + d4 * 4] = v;
    }

    float4 kp[2], vp[2];
    const int sp0 = tid >> 5, sd4 = tid & 31;   // f4 id tid: (p, d4); tid+256 -> p+8

    auto issue = [&](int t) {
        const int pb = split + t * SPLITS;
        const int blk = bt[b * MAXPB + pb];
        const int s0 = pb * 16;
        #pragma unroll
        for (int j = 0; j < 2; ++j) {
            const int p = sp0 + j * 8;
            const int s = s0 + p;
            size_t coff = (((size_t)blk * 16 + p) * 2 + kh) * 128 + sd4 * 4;
            size_t noff = ((size_t)(b * 2 + kh)) * 128 + sd4 * 4;
            kp[j] = (s == len - 1) ? *(const float4*)&knew[noff]
                                   : *(const float4*)&kcache[coff];
            vp[j] = (s == len - 1) ? *(const float4*)&vnew[noff]
                                   : *(const float4*)&vcache[coff];
        }
    };
    auto commit = [&]() {
        #pragma unroll
        for (int j = 0; j < 2; ++j) {
            const int p = sp0 + j * 8;
            *(float4*)&sK[p * 132 + sd4 * 4] = kp[j];
            *(float4*)&sV[p * 132 + sd4 * 4] = vp[j];
        }
    };

    issue(0);
    commit();
    __syncthreads();

    float m = -INFINITY, l = 0.f;
    float4 o0 = make_float4(0.f, 0.f, 0.f, 0.f);
    float4 o1 = make_float4(0.f, 0.f, 0.f, 0.f);

    for (int t = 0; t < nt; ++t) {
        if (t + 1 < nt) issue(t + 1);
        const int s0 = (split + t * SPLITS) * 16;

        // ---- QK^T: one dot per lane
        const float* qrow = &sQ[g * 132];
        const float* krow = &sK[sub * 132];
        float dd[4] = {0.f, 0.f, 0.f, 0.f};
        #pragma unroll
        for (int u = 0; u < 8; ++u) {
            #pragma unroll
            for (int v2 = 0; v2 < 4; ++v2) {
                float4 qa = *(const float4*)&qrow[(u * 4 + v2) * 4];
                float4 ka = *(const float4*)&krow[(u * 4 + v2) * 4];
                dd[v2] += qa.x * ka.x + qa.y * ka.y + qa.z * ka.z + qa.w * ka.w;
            }
        }
        float sc = (dd[0] + dd[1]) + (dd[2] + dd[3]);
        if (s0 + sub >= len) sc = -INFINITY;

        // ---- online softmax over 16 positions (width-16 butterflies)
        float tmax = sc;
        tmax = fmaxf(tmax, __shfl_xor(tmax, 1, 16));
        tmax = fmaxf(tmax, __shfl_xor(tmax, 2, 16));
        tmax = fmaxf(tmax, __shfl_xor(tmax, 4, 16));
        tmax = fmaxf(tmax, __shfl_xor(tmax, 8, 16));
        const float m_new = fmaxf(m, tmax);
        const float corr = expf(m - m_new);
        const float pe = expf(sc - m_new);
        float ls = pe;
        ls += __shfl_xor(ls, 1, 16);
        ls += __shfl_xor(ls, 2, 16);
        ls += __shfl_xor(ls, 4, 16);
        ls += __shfl_xor(ls, 8, 16);
        l = l * corr + ls;
        m = m_new;
        o0.x *= corr; o0.y *= corr; o0.z *= corr; o0.w *= corr;
        o1.x *= corr; o1.y *= corr; o1.z *= corr; o1.w *= corr;

        // ---- PV: lane=(gl, dq=sub) accumulates O[g][sub*8..+8]
        #pragma unroll
        for (int p = 0; p < 16; ++p) {
            const float pev = __shfl(pe, p, 16);
            const float* vr = &sV[p * 132 + sub * 8];
            float4 va = *(const float4*)&vr[0];
            float4 vb = *(const float4*)&vr[4];
            o0.x += pev * va.x; o0.y += pev * va.y;
            o0.z += pev * va.z; o0.w += pev * va.w;
            o1.x += pev * vb.x; o1.y += pev * vb.y;
            o1.z += pev * vb.z; o1.w += pev * vb.w;
        }
        __syncthreads();
        if (t + 1 < nt) { commit(); __syncthreads(); }
    }

    size_t base = ((((size_t)(b * 2 + kh)) * SPLITS + split) * 16 + g) * 128 + sub * 8;
    *(float4*)&pO[base] = o0;
    *(float4*)&pO[base + 4] = o1;
    if (sub == 0) {
        size_t mb = ((((size_t)(b * 2 + kh)) * SPLITS + split) * 16 + g) * 2;
        pML[mb] = m;
        pML[mb + 1] = l;
    }
}

__global__ __launch_bounds__(256) void attn_combine(
    const float* __restrict__ pO, const float* __restrict__ pML,
    float* __restrict__ aout)
{
    const int bk = blockIdx.x;
    const int tid = threadIdx.x;
    const int g = tid >> 4;
    const int dh = tid & 15;

    float ms[SPLITS], ls[SPLITS];
    float M = -INFINITY;
    #pragma unroll
    for (int s = 0; s < SPLITS; ++s) {
        size_t mb = (((size_t)bk * SPLITS + s) * 16 + g) * 2;
        ms[s] = pML[mb]; ls[s] = pML[mb + 1];
        M = fmaxf(M, ms[s]);
    }
    float L = 0.f;
    #pragma unroll
    for (int s = 0; s < SPLITS; ++s) L += ls[s] * expf(ms[s] - M);

    float acc[8] = {0, 0, 0, 0, 0, 0, 0, 0};
    #pragma unroll
    for (int s = 0; s < SPLITS; ++s) {
        float wgt = expf(ms[s] - M);
        const float* src = &pO[(((size_t)bk * SPLITS + s) * 16 + g) * 128 + dh * 8];
        #pragma unroll
        for (int r = 0; r < 8; ++r) acc[r] += wgt * src[r];
    }
    const float invL = 1.f / L;
    const int b = bk >> 1, kh = bk & 1;
    float* dst = &aout[(size_t)b * 4096 + (kh * 16 + g) * 128 + dh * 8];
    #pragma unroll
    for (int r = 0; r < 8; ++r) dst[r] = acc[r] * invL;
}

__global__ __launch_bounds__(256) void reduce_dense(
    const float* __restrict__ part, float* __restrict__ out)
{
    const int b = blockIdx.y;
    const int col = (blockIdx.x * 256 + threadIdx.x) * 4;
    float4 s = make_float4(0.f, 0.f, 0.f, 0.f);
    #pragma unroll
    for (int ks = 0; ks < KSPLIT; ++ks) {
        float4 v = *(const float4*)&part[((size_t)ks * 64 + b) * NDENSE + col];
        s.x += v.x; s.y += v.y; s.z += v.z; s.w += v.w;
    }
    *(float4*)&out[(size_t)b * 4096 + col] = s;
}

extern "C" void kernel_launch(void* const* d_in, const int* in_sizes, int n_in,
                              void* d_out, int out_size, void* d_ws, size_t ws_size,
                              hipStream_t stream) {
    const float* hidden = (const float*)d_in[0];
    const float* wqkv   = (const float*)d_in[1];
    const float* wdense = (const float*)d_in[2];
    const float* kcache = (const float*)d_in[3];
    const float* vcache = (const float*)d_in[4];
    const int*   bt     = (const int*)d_in[5];
    const int*   lens   = (const int*)d_in[7];
    float* out = (float*)d_out;

    float* ws     = (float*)d_ws;
    float* q_rope = ws;                  // 262144
    float* k_new  = ws + 262144;         // 16384
    float* v_new  = ws + 278528;         // 16384
    float* aout   = ws + 294912;         // 262144
    float* regX   = ws + 557056;         // shared region, max 2359296 f
    float* pO     = regX;                // 2097152 (attn phase)
    float* pML    = ws + 2654208;        // 32768
    // total ws use: 2916352 floats = 11.7 MB

    gemm_splitk<<<dim3(NQKV / 16, KSPLIT), dim3(256), 0, stream>>>(
        hidden, wqkv, regX, NQKV);
    reduce_qkv<<<dim3(9, 64), dim3(256), 0, stream>>>(
        regX, lens, q_rope, k_new, v_new);
    attn_partial<<<dim3(SPLITS, 2, 64), dim3(256), 0, stream>>>(
        q_rope, k_new, v_new, kcache, vcache, bt, lens, pO, pML);
    attn_combine<<<dim3(128), dim3(256), 0, stream>>>(pO, pML, aout);
    gemm_splitk<<<dim3(NDENSE / 16, KSPLIT), dim3(256), 0, stream>>>(
        aout, wdense, regX, NDENSE);
    reduce_dense<<<dim3(4, 64), dim3(256), 0, stream>>>(regX, out);
}

// Round 4
// 294.462 us; speedup vs baseline: 1.7219x; 1.6016x over previous
//
#include <hip/hip_runtime.h>
#include <math.h>

#define KDIM 4096
#define SPLITS 8
#define WAYS 32
#define MAXPB 256
#define NQKV 4608
#define NDENSE 4096
#define KSPLIT 8
#define KRANGE 512

typedef __attribute__((ext_vector_type(8))) short bh8;
typedef __attribute__((ext_vector_type(4))) float f32x4;

__device__ __forceinline__ short f2bf(float x) {
    union { float f; unsigned u; } v; v.f = x;
    unsigned r = v.u + 0x7FFFu + ((v.u >> 16) & 1u);   // RNE
    return (short)(r >> 16);
}

__device__ __forceinline__ void rope_rotate(float& x0, float& x1, int j, int pos) {
    double inv = pow(10000.0, -(double)j / 32.0);
    double ang = (double)pos * inv;
    float c = (float)cos(ang), s = (float)sin(ang);
    float r0 = x0 * c - x1 * s;
    float r1 = x1 * c + x0 * s;
    x0 = r0; x1 = r1;
}

// Split-K GEMM (unchanged from round 3).
__global__ __launch_bounds__(256) void gemm_splitk(
    const float* __restrict__ A, const float* __restrict__ W,
    float* __restrict__ part, int N)
{
    __shared__ __align__(16) float sA[64 * 68];
    __shared__ __align__(16) float sW[16 * 68];
    const int tid = threadIdx.x;
    const int n0 = blockIdx.x * 16;
    const int ks = blockIdx.y;
    const int w = tid >> 6;
    const int lane = tid & 63;
    const int kbase0 = ks * KRANGE;
    const int wr = tid >> 4, wkq = tid & 15;

    float acc[4] = {0.f, 0.f, 0.f, 0.f};
    float4 apre[4]; float4 wpre;

    #pragma unroll
    for (int j = 0; j < 4; ++j) {
        int id = tid + j * 256; int bb = id >> 4, kq = id & 15;
        apre[j] = *(const float4*)&A[(size_t)bb * KDIM + kbase0 + kq * 4];
    }
    wpre = *(const float4*)&W[(size_t)(n0 + wr) * KDIM + kbase0 + wkq * 4];
    #pragma unroll
    for (int j = 0; j < 4; ++j) {
        int id = tid + j * 256; int bb = id >> 4, kq = id & 15;
        *(float4*)&sA[bb * 68 + kq * 4] = apre[j];
    }
    *(float4*)&sW[wr * 68 + wkq * 4] = wpre;
    __syncthreads();

    for (int t = 0; t < 8; ++t) {
        if (t + 1 < 8) {
            const int kb = kbase0 + (t + 1) * 64;
            #pragma unroll
            for (int j = 0; j < 4; ++j) {
                int id = tid + j * 256; int bb = id >> 4, kq = id & 15;
                apre[j] = *(const float4*)&A[(size_t)bb * KDIM + kb + kq * 4];
            }
            wpre = *(const float4*)&W[(size_t)(n0 + wr) * KDIM + kb + wkq * 4];
        }
        #pragma unroll
        for (int sub = 0; sub < 2; ++sub) {
            float4 areg[8];
            #pragma unroll
            for (int j = 0; j < 8; ++j)
                areg[j] = *(const float4*)&sA[lane * 68 + sub * 32 + j * 4];
            #pragma unroll
            for (int i = 0; i < 4; ++i) {
                const float* wrow = &sW[(w * 4 + i) * 68 + sub * 32];
                #pragma unroll
                for (int j = 0; j < 8; ++j) {
                    float4 w4 = *(const float4*)&wrow[j * 4];
                    acc[i] += areg[j].x * w4.x + areg[j].y * w4.y
                            + areg[j].z * w4.z + areg[j].w * w4.w;
                }
            }
        }
        __syncthreads();
        if (t + 1 < 8) {
            #pragma unroll
            for (int j = 0; j < 4; ++j) {
                int id = tid + j * 256; int bb = id >> 4, kq = id & 15;
                *(float4*)&sA[bb * 68 + kq * 4] = apre[j];
            }
            *(float4*)&sW[wr * 68 + wkq * 4] = wpre;
            __syncthreads();
        }
    }
    *(float4*)&part[((size_t)ks * 64 + lane) * N + n0 + w * 4] =
        make_float4(acc[0], acc[1], acc[2], acc[3]);
}

__global__ __launch_bounds__(256) void reduce_qkv(
    const float* __restrict__ part, const int* __restrict__ lens,
    float* __restrict__ q_rope, float* __restrict__ knew, float* __restrict__ vnew)
{
    const int b = blockIdx.y;
    const int c0 = (blockIdx.x * 256 + threadIdx.x) * 2;
    float x0 = 0.f, x1 = 0.f;
    #pragma unroll
    for (int ks = 0; ks < KSPLIT; ++ks) {
        float2 v = *(const float2*)&part[((size_t)ks * 64 + b) * NQKV + c0];
        x0 += v.x; x1 += v.y;
    }
    const int pos = lens[b] - 1;
    if (c0 < 4096) {
        const int d = c0 & 127;
        if (d < 64) rope_rotate(x0, x1, d >> 1, pos);
        q_rope[(size_t)b * 4096 + c0] = x0;
        q_rope[(size_t)b * 4096 + c0 + 1] = x1;
    } else if (c0 < 4352) {
        const int kidx = c0 - 4096, kh = kidx >> 7, d = kidx & 127;
        if (d < 64) rope_rotate(x0, x1, d >> 1, pos);
        knew[(b * 2 + kh) * 128 + d] = x0;
        knew[(b * 2 + kh) * 128 + d + 1] = x1;
    } else {
        const int vidx = c0 - 4352, kh = vidx >> 7, d = vidx & 127;
        vnew[(b * 2 + kh) * 128 + d] = x0;
        vnew[(b * 2 + kh) * 128 + d + 1] = x1;
    }
}

// MFMA flash-decode. Grid (split, kh, b), 256 thr = 4 waves, way = split*4+wv.
// Per 32-pos chunk: S^T[32p][16g] = K*Q^T (8 mfma, K global->reg, Q in regs);
// in-reg online softmax (lane owns head g=l&15, 8 p-regs, 2 shfl_xor);
// P relay via 1KB LDS; O^T[128d][16g] += V^T*P^T (8 mfma, V global->reg).
__global__ __launch_bounds__(256) void attn_mfma(
    const float* __restrict__ qr, const float* __restrict__ knew,
    const float* __restrict__ vnew, const float* __restrict__ kcache,
    const float* __restrict__ vcache, const int* __restrict__ bt,
    const int* __restrict__ lens, float* __restrict__ pO, float* __restrict__ pML)
{
    const int split = blockIdx.x;
    const int kh = blockIdx.y;
    const int b = blockIdx.z;
    const int tid = threadIdx.x;
    const int wv = tid >> 6;
    const int l = tid & 63;
    const int g = l & 15;      // head (S^T col / O^T col)
    const int h = l >> 4;      // 16-lane group
    const int way = split * 4 + wv;

    __shared__ unsigned int sP[4][256];        // P relay: [wave][16g x 16u32]
    __shared__ float sO[3][16][132];           // merge: waves 1..3 O^T
    __shared__ float sML[3][2][16];

    const int len = lens[b];
    const int nchunks = (len + 31) >> 5;       // len>=1024 -> nchunks>=32=WAYS
    const size_t nbase = ((size_t)(b * 2 + kh)) * 128;

    // Q B-fragments (scale folded in): qf[dc][e] = Q[g][32dc+8h+e]*scale
    const float scale = 0.08838834764831845f;
    bh8 qf[4];
    {
        const float* qrow = &qr[((size_t)(b * 32 + kh * 16 + g)) * 128 + h * 8];
        #pragma unroll
        for (int dc = 0; dc < 4; ++dc) {
            float4 a = *(const float4*)&qrow[dc * 32];
            float4 c = *(const float4*)&qrow[dc * 32 + 4];
            qf[dc][0] = f2bf(a.x * scale); qf[dc][1] = f2bf(a.y * scale);
            qf[dc][2] = f2bf(a.z * scale); qf[dc][3] = f2bf(a.w * scale);
            qf[dc][4] = f2bf(c.x * scale); qf[dc][5] = f2bf(c.y * scale);
            qf[dc][6] = f2bf(c.z * scale); qf[dc][7] = f2bf(c.w * scale);
        }
    }

    float m = -INFINITY, lacc = 0.f;
    f32x4 oacc[8];
    #pragma unroll
    for (int dt = 0; dt < 8; ++dt) oacc[dt] = (f32x4){0.f, 0.f, 0.f, 0.f};

    for (int c = way; c < nchunks; c += WAYS) {
        const int s0 = c * 32;
        const int blk0 = bt[b * MAXPB + 2 * c];
        const int blk1 = bt[b * MAXPB + 2 * c + 1];

        // ---- K loads (A-frag slices: row p = 16ph + g, dims 32dc+8h..+8)
        const float* rowK0 = (s0 + g == len - 1) ? &knew[nbase]
            : &kcache[(((size_t)blk0 * 16 + g) * 2 + kh) * 128];
        const float* rowK1 = (s0 + 16 + g == len - 1) ? &knew[nbase]
            : &kcache[(((size_t)blk1 * 16 + g) * 2 + kh) * 128];
        float4 k0[8], k1[8];
        #pragma unroll
        for (int dc = 0; dc < 4; ++dc) {
            k0[2*dc]   = *(const float4*)&rowK0[dc * 32 + h * 8];
            k0[2*dc+1] = *(const float4*)&rowK0[dc * 32 + h * 8 + 4];
            k1[2*dc]   = *(const float4*)&rowK1[dc * 32 + h * 8];
            k1[2*dc+1] = *(const float4*)&rowK1[dc * 32 + h * 8 + 4];
        }

        // ---- V loads (column slices: vv[e][dt] = V[8h+e][16dt+g])
        float vv[8][8];
        #pragma unroll
        for (int e = 0; e < 8; ++e) {
            const int p = h * 8 + e;
            const int s = s0 + p;
            const float* rowV = (s == len - 1) ? &vnew[nbase]
                : &vcache[(((size_t)(p < 16 ? blk0 : blk1) * 16 + (p & 15)) * 2 + kh) * 128];
            #pragma unroll
            for (int dt = 0; dt < 8; ++dt)
                vv[e][dt] = rowV[dt * 16 + g];
        }

        // ---- QK^T: S^T tiles (ph=0,1), contract over d in 4 slices of 32
        f32x4 sa0 = (f32x4){0.f,0.f,0.f,0.f};
        f32x4 sa1 = (f32x4){0.f,0.f,0.f,0.f};
        #pragma unroll
        for (int dc = 0; dc < 4; ++dc) {
            bh8 a0, a1;
            a0[0]=f2bf(k0[2*dc].x);   a0[1]=f2bf(k0[2*dc].y);
            a0[2]=f2bf(k0[2*dc].z);   a0[3]=f2bf(k0[2*dc].w);
            a0[4]=f2bf(k0[2*dc+1].x); a0[5]=f2bf(k0[2*dc+1].y);
            a0[6]=f2bf(k0[2*dc+1].z); a0[7]=f2bf(k0[2*dc+1].w);
            a1[0]=f2bf(k1[2*dc].x);   a1[1]=f2bf(k1[2*dc].y);
            a1[2]=f2bf(k1[2*dc].z);   a1[3]=f2bf(k1[2*dc].w);
            a1[4]=f2bf(k1[2*dc+1].x); a1[5]=f2bf(k1[2*dc+1].y);
            a1[6]=f2bf(k1[2*dc+1].z); a1[7]=f2bf(k1[2*dc+1].w);
            sa0 = __builtin_amdgcn_mfma_f32_16x16x32_bf16(a0, qf[dc], sa0, 0, 0, 0);
            sa1 = __builtin_amdgcn_mfma_f32_16x16x32_bf16(a1, qf[dc], sa1, 0, 0, 0);
        }

        // ---- online softmax (per head g; p-values: 8 regs x 4 h-lanes)
        float sc[8];
        #pragma unroll
        for (int j = 0; j < 4; ++j) {
            sc[j]     = (s0 + 4*h + j      < len) ? sa0[j] : -INFINITY;
            sc[4 + j] = (s0 + 16 + 4*h + j < len) ? sa1[j] : -INFINITY;
        }
        float tmax = sc[0];
        #pragma unroll
        for (int j = 1; j < 8; ++j) tmax = fmaxf(tmax, sc[j]);
        tmax = fmaxf(tmax, __shfl_xor(tmax, 16));
        tmax = fmaxf(tmax, __shfl_xor(tmax, 32));
        const float m_new = fmaxf(m, tmax);
        const float corr = expf(m - m_new);       // first chunk: exp(-inf)=0
        float pe[8], ls = 0.f;
        #pragma unroll
        for (int j = 0; j < 8; ++j) { pe[j] = expf(sc[j] - m_new); ls += pe[j]; }
        ls += __shfl_xor(ls, 16);
        ls += __shfl_xor(ls, 32);
        lacc = lacc * corr + ls;
        m = m_new;
        #pragma unroll
        for (int dt = 0; dt < 8; ++dt) {
            oacc[dt][0] *= corr; oacc[dt][1] *= corr;
            oacc[dt][2] *= corr; oacc[dt][3] *= corr;
        }

        // ---- P relay: D-layout -> B-frag layout via 1KB LDS (wave-local)
        unsigned int* myP = sP[wv];
        #pragma unroll
        for (int ph = 0; ph < 2; ++ph)
            #pragma unroll
            for (int t2 = 0; t2 < 2; ++t2) {
                unsigned lo = (unsigned short)f2bf(pe[ph*4 + 2*t2]);
                unsigned hi = (unsigned short)f2bf(pe[ph*4 + 2*t2 + 1]);
                myP[g * 16 + ph * 8 + 2 * h + t2] = lo | (hi << 16);
            }
        asm volatile("s_waitcnt lgkmcnt(0)" ::: "memory");
        bh8 pf = *(const bh8*)&myP[g * 16 + 4 * h];

        // ---- PV: O^T[16dt+m][g] += V^T * P^T
        #pragma unroll
        for (int dt = 0; dt < 8; ++dt) {
            bh8 av;
            #pragma unroll
            for (int e = 0; e < 8; ++e) av[e] = f2bf(vv[e][dt]);
            oacc[dt] = __builtin_amdgcn_mfma_f32_16x16x32_bf16(av, pf, oacc[dt], 0, 0, 0);
        }
    }

    // ---- 4-way in-block merge
    if (wv > 0) {
        #pragma unroll
        for (int dt = 0; dt < 8; ++dt)
            #pragma unroll
            for (int j = 0; j < 4; ++j)
                sO[wv-1][g][dt*16 + 4*h + j] = oacc[dt][j];
        if (l < 16) {
            sML[wv-1][0][g] = m;
            sML[wv-1][1][g] = lacc;
        }
    }
    __syncthreads();
    if (wv == 0) {
        float M = m;
        #pragma unroll
        for (int i = 0; i < 3; ++i) M = fmaxf(M, sML[i][0][g]);
        const float w0 = expf(m - M);
        float L = lacc * w0;
        float wi[3];
        #pragma unroll
        for (int i = 0; i < 3; ++i) {
            wi[i] = expf(sML[i][0][g] - M);
            L += sML[i][1][g] * wi[i];
        }
        size_t base = ((((size_t)(b * 2 + kh)) * SPLITS + split) * 16 + g) * 128;
        #pragma unroll
        for (int dt = 0; dt < 8; ++dt)
            #pragma unroll
            for (int j = 0; j < 4; ++j) {
                float o = oacc[dt][j] * w0;
                #pragma unroll
                for (int i = 0; i < 3; ++i)
                    o += sO[i][g][dt*16 + 4*h + j] * wi[i];
                pO[base + dt*16 + 4*h + j] = o;
            }
        if (l < 16) {
            size_t mb = ((((size_t)(b * 2 + kh)) * SPLITS + split) * 16 + g) * 2;
            pML[mb] = M;
            pML[mb + 1] = L;
        }
    }
}

__global__ __launch_bounds__(256) void attn_combine(
    const float* __restrict__ pO, const float* __restrict__ pML,
    float* __restrict__ aout)
{
    const int bk = blockIdx.x;
    const int tid = threadIdx.x;
    const int g = tid >> 4;
    const int dh = tid & 15;

    float ms[SPLITS], ls[SPLITS];
    float M = -INFINITY;
    #pragma unroll
    for (int s = 0; s < SPLITS; ++s) {
        size_t mb = (((size_t)bk * SPLITS + s) * 16 + g) * 2;
        ms[s] = pML[mb]; ls[s] = pML[mb + 1];
        M = fmaxf(M, ms[s]);
    }
    float L = 0.f;
    #pragma unroll
    for (int s = 0; s < SPLITS; ++s) L += ls[s] * expf(ms[s] - M);

    float acc[8] = {0, 0, 0, 0, 0, 0, 0, 0};
    #pragma unroll
    for (int s = 0; s < SPLITS; ++s) {
        float wgt = expf(ms[s] - M);
        const float* src = &pO[(((size_t)bk * SPLITS + s) * 16 + g) * 128 + dh * 8];
        #pragma unroll
        for (int r = 0; r < 8; ++r) acc[r] += wgt * src[r];
    }
    const float invL = 1.f / L;
    const int b = bk >> 1, kh = bk & 1;
    float* dst = &aout[(size_t)b * 4096 + (kh * 16 + g) * 128 + dh * 8];
    #pragma unroll
    for (int r = 0; r < 8; ++r) dst[r] = acc[r] * invL;
}

__global__ __launch_bounds__(256) void reduce_dense(
    const float* __restrict__ part, float* __restrict__ out)
{
    const int b = blockIdx.y;
    const int col = (blockIdx.x * 256 + threadIdx.x) * 4;
    float4 s = make_float4(0.f, 0.f, 0.f, 0.f);
    #pragma unroll
    for (int ks = 0; ks < KSPLIT; ++ks) {
        float4 v = *(const float4*)&part[((size_t)ks * 64 + b) * NDENSE + col];
        s.x += v.x; s.y += v.y; s.z += v.z; s.w += v.w;
    }
    *(float4*)&out[(size_t)b * 4096 + col] = s;
}

extern "C" void kernel_launch(void* const* d_in, const int* in_sizes, int n_in,
                              void* d_out, int out_size, void* d_ws, size_t ws_size,
                              hipStream_t stream) {
    const float* hidden = (const float*)d_in[0];
    const float* wqkv   = (const float*)d_in[1];
    const float* wdense = (const float*)d_in[2];
    const float* kcache = (const float*)d_in[3];
    const float* vcache = (const float*)d_in[4];
    const int*   bt     = (const int*)d_in[5];
    const int*   lens   = (const int*)d_in[7];
    float* out = (float*)d_out;

    float* ws     = (float*)d_ws;
    float* q_rope = ws;                  // 262144
    float* k_new  = ws + 262144;         // 16384
    float* v_new  = ws + 278528;         // 16384
    float* aout   = ws + 294912;         // 262144
    float* regX   = ws + 557056;         // shared region (gemm partials / pO)
    float* pO     = regX;                // 2097152 (attn phase)
    float* pML    = ws + 2654208;        // 32768
    // total ws use: 2916352 floats = 11.7 MB

    gemm_splitk<<<dim3(NQKV / 16, KSPLIT), dim3(256), 0, stream>>>(
        hidden, wqkv, regX, NQKV);
    reduce_qkv<<<dim3(9, 64), dim3(256), 0, stream>>>(
        regX, lens, q_rope, k_new, v_new);
    attn_mfma<<<dim3(SPLITS, 2, 64), dim3(256), 0, stream>>>(
        q_rope, k_new, v_new, kcache, vcache, bt, lens, pO, pML);
    attn_combine<<<dim3(128), dim3(256), 0, stream>>>(pO, pML, aout);
    gemm_splitk<<<dim3(NDENSE / 16, KSPLIT), dim3(256), 0, stream>>>(
        aout, wdense, regX, NDENSE);
    reduce_dense<<<dim3(4, 64), dim3(256), 0, stream>>>(regX, out);
}

// Round 5
// 211.506 us; speedup vs baseline: 2.3972x; 1.3922x over previous
//
#include <hip/hip_runtime.h>
#include <math.h>

#define KDIM 4096
#define SPLITS 8
#define WAYS 32
#define MAXPB 256
#define NQKV 4608
#define NDENSE 4096
#define KSPLIT 8
#define KRANGE 512

typedef __attribute__((ext_vector_type(8))) short bh8;
typedef __attribute__((ext_vector_type(4))) float f32x4;

__device__ __forceinline__ short f2bf(float x) {
    union { float f; unsigned u; } v; v.f = x;
    unsigned r = v.u + 0x7FFFu + ((v.u >> 16) & 1u);   // RNE
    return (short)(r >> 16);
}
__device__ __forceinline__ float bf2f(short h) {
    union { unsigned u; float f; } v;
    v.u = ((unsigned)(unsigned short)h) << 16;
    return v.f;
}

__device__ __forceinline__ void rope_rotate(float& x0, float& x1, int j, int pos) {
    double inv = pow(10000.0, -(double)j / 32.0);
    double ang = (double)pos * inv;
    float c = (float)cos(ang), s = (float)sin(ang);
    float r0 = x0 * c - x1 * s;
    float r1 = x1 * c + x0 * s;
    x0 = r0; x1 = r1;
}

// Split x[64][4096] f32 -> hi,lo bf16 (hi = RNE(x), lo = RNE(x - hi)).
__global__ __launch_bounds__(256) void prep_hilo(
    const float* __restrict__ x, unsigned short* __restrict__ hi,
    unsigned short* __restrict__ lo)
{
    const int i = (blockIdx.x * 256 + threadIdx.x) * 4;
    float4 v = *(const float4*)&x[i];
    unsigned short h4[4], l4[4];
    float vf[4] = {v.x, v.y, v.z, v.w};
    #pragma unroll
    for (int j = 0; j < 4; ++j) {
        short hh = f2bf(vf[j]);
        h4[j] = (unsigned short)hh;
        l4[j] = (unsigned short)f2bf(vf[j] - bf2f(hh));
    }
    *(ushort4*)&hi[i] = make_ushort4(h4[0], h4[1], h4[2], h4[3]);
    *(ushort4*)&lo[i] = make_ushort4(l4[0], l4[1], l4[2], l4[3]);
}

// MFMA split-K GEMM: part[ks][64][N] = A[64][K-slice] * W[N][K-slice]^T.
// A pre-split to bf16 hi/lo (L2-resident); W f32 streamed, hi/lo split in-reg.
// acc += ah*wh + al*wh + ah*wl  (al*wl ~2^-18, dropped).
// Block 256 = 4 waves; wave wv owns n-cols [bx*64+wv*16, +16), all 64 m-rows.
// No LDS, no syncthreads.
__global__ __launch_bounds__(256) void gemm_mfma(
    const unsigned short* __restrict__ A_hi, const unsigned short* __restrict__ A_lo,
    const float* __restrict__ W, float* __restrict__ part, int N)
{
    const int tid = threadIdx.x;
    const int wv = tid >> 6;
    const int l = tid & 63;
    const int lr = l & 15;          // row/col-in-tile selector
    const int h = l >> 4;           // k-window
    const int n0 = blockIdx.x * 64 + wv * 16;
    const int k0 = blockIdx.y * KRANGE;

    const float* wrow = &W[(size_t)(n0 + lr) * KDIM + h * 8];
    const unsigned short* pah[4];
    const unsigned short* pal[4];
    #pragma unroll
    for (int mt = 0; mt < 4; ++mt) {
        pah[mt] = &A_hi[(mt * 16 + lr) * KDIM + h * 8];
        pal[mt] = &A_lo[(mt * 16 + lr) * KDIM + h * 8];
    }

    f32x4 acc[4];
    #pragma unroll
    for (int mt = 0; mt < 4; ++mt) acc[mt] = (f32x4){0.f, 0.f, 0.f, 0.f};

    float4 wc0, wc1, wn0, wn1;
    bh8 ahc[4], alc[4], ahn[4], aln[4];

    wc0 = *(const float4*)&wrow[k0];
    wc1 = *(const float4*)&wrow[k0 + 4];
    #pragma unroll
    for (int mt = 0; mt < 4; ++mt) {
        ahc[mt] = *(const bh8*)&pah[mt][k0];
        alc[mt] = *(const bh8*)&pal[mt][k0];
    }

    for (int kt = 0; kt < KRANGE / 32; ++kt) {
        if (kt + 1 < KRANGE / 32) {
            const int kn = k0 + (kt + 1) * 32;
            wn0 = *(const float4*)&wrow[kn];
            wn1 = *(const float4*)&wrow[kn + 4];
            #pragma unroll
            for (int mt = 0; mt < 4; ++mt) {
                ahn[mt] = *(const bh8*)&pah[mt][kn];
                aln[mt] = *(const bh8*)&pal[mt][kn];
            }
        }
        // split W to hi/lo bf16
        bh8 whi, wlo;
        float wf[8] = {wc0.x, wc0.y, wc0.z, wc0.w, wc1.x, wc1.y, wc1.z, wc1.w};
        #pragma unroll
        for (int e = 0; e < 8; ++e) {
            short hh = f2bf(wf[e]);
            whi[e] = hh;
            wlo[e] = f2bf(wf[e] - bf2f(hh));
        }
        #pragma unroll
        for (int mt = 0; mt < 4; ++mt) {
            acc[mt] = __builtin_amdgcn_mfma_f32_16x16x32_bf16(ahc[mt], whi, acc[mt], 0, 0, 0);
            acc[mt] = __builtin_amdgcn_mfma_f32_16x16x32_bf16(alc[mt], whi, acc[mt], 0, 0, 0);
            acc[mt] = __builtin_amdgcn_mfma_f32_16x16x32_bf16(ahc[mt], wlo, acc[mt], 0, 0, 0);
        }
        wc0 = wn0; wc1 = wn1;
        #pragma unroll
        for (int mt = 0; mt < 4; ++mt) { ahc[mt] = ahn[mt]; alc[mt] = aln[mt]; }
    }

    // D layout: col = l&15 (n), row = h*4 + j (m within tile)
    const int ks = blockIdx.y;
    #pragma unroll
    for (int mt = 0; mt < 4; ++mt) {
        const int m = mt * 16 + h * 4;
        #pragma unroll
        for (int j = 0; j < 4; ++j)
            part[((size_t)ks * 64 + m + j) * N + n0 + lr] = acc[mt][j];
    }
}

__global__ __launch_bounds__(256) void reduce_qkv(
    const float* __restrict__ part, const int* __restrict__ lens,
    float* __restrict__ q_rope, float* __restrict__ knew, float* __restrict__ vnew)
{
    const int b = blockIdx.y;
    const int c0 = (blockIdx.x * 256 + threadIdx.x) * 2;
    float x0 = 0.f, x1 = 0.f;
    #pragma unroll
    for (int ks = 0; ks < KSPLIT; ++ks) {
        float2 v = *(const float2*)&part[((size_t)ks * 64 + b) * NQKV + c0];
        x0 += v.x; x1 += v.y;
    }
    const int pos = lens[b] - 1;
    if (c0 < 4096) {
        const int d = c0 & 127;
        if (d < 64) rope_rotate(x0, x1, d >> 1, pos);
        q_rope[(size_t)b * 4096 + c0] = x0;
        q_rope[(size_t)b * 4096 + c0 + 1] = x1;
    } else if (c0 < 4352) {
        const int kidx = c0 - 4096, kh = kidx >> 7, d = kidx & 127;
        if (d < 64) rope_rotate(x0, x1, d >> 1, pos);
        knew[(b * 2 + kh) * 128 + d] = x0;
        knew[(b * 2 + kh) * 128 + d + 1] = x1;
    } else {
        const int vidx = c0 - 4352, kh = vidx >> 7, d = vidx & 127;
        vnew[(b * 2 + kh) * 128 + d] = x0;
        vnew[(b * 2 + kh) * 128 + d + 1] = x1;
    }
}

// MFMA flash-decode (unchanged from round 4).
__global__ __launch_bounds__(256) void attn_mfma(
    const float* __restrict__ qr, const float* __restrict__ knew,
    const float* __restrict__ vnew, const float* __restrict__ kcache,
    const float* __restrict__ vcache, const int* __restrict__ bt,
    const int* __restrict__ lens, float* __restrict__ pO, float* __restrict__ pML)
{
    const int split = blockIdx.x;
    const int kh = blockIdx.y;
    const int b = blockIdx.z;
    const int tid = threadIdx.x;
    const int wv = tid >> 6;
    const int l = tid & 63;
    const int g = l & 15;
    const int h = l >> 4;
    const int way = split * 4 + wv;

    __shared__ unsigned int sP[4][256];
    __shared__ float sO[3][16][132];
    __shared__ float sML[3][2][16];

    const int len = lens[b];
    const int nchunks = (len + 31) >> 5;
    const size_t nbase = ((size_t)(b * 2 + kh)) * 128;

    const float scale = 0.08838834764831845f;
    bh8 qf[4];
    {
        const float* qrow = &qr[((size_t)(b * 32 + kh * 16 + g)) * 128 + h * 8];
        #pragma unroll
        for (int dc = 0; dc < 4; ++dc) {
            float4 a = *(const float4*)&qrow[dc * 32];
            float4 c = *(const float4*)&qrow[dc * 32 + 4];
            qf[dc][0] = f2bf(a.x * scale); qf[dc][1] = f2bf(a.y * scale);
            qf[dc][2] = f2bf(a.z * scale); qf[dc][3] = f2bf(a.w * scale);
            qf[dc][4] = f2bf(c.x * scale); qf[dc][5] = f2bf(c.y * scale);
            qf[dc][6] = f2bf(c.z * scale); qf[dc][7] = f2bf(c.w * scale);
        }
    }

    float m = -INFINITY, lacc = 0.f;
    f32x4 oacc[8];
    #pragma unroll
    for (int dt = 0; dt < 8; ++dt) oacc[dt] = (f32x4){0.f, 0.f, 0.f, 0.f};

    for (int c = way; c < nchunks; c += WAYS) {
        const int s0 = c * 32;
        const int blk0 = bt[b * MAXPB + 2 * c];
        const int blk1 = bt[b * MAXPB + 2 * c + 1];

        const float* rowK0 = (s0 + g == len - 1) ? &knew[nbase]
            : &kcache[(((size_t)blk0 * 16 + g) * 2 + kh) * 128];
        const float* rowK1 = (s0 + 16 + g == len - 1) ? &knew[nbase]
            : &kcache[(((size_t)blk1 * 16 + g) * 2 + kh) * 128];
        float4 k0[8], k1[8];
        #pragma unroll
        for (int dc = 0; dc < 4; ++dc) {
            k0[2*dc]   = *(const float4*)&rowK0[dc * 32 + h * 8];
            k0[2*dc+1] = *(const float4*)&rowK0[dc * 32 + h * 8 + 4];
            k1[2*dc]   = *(const float4*)&rowK1[dc * 32 + h * 8];
            k1[2*dc+1] = *(const float4*)&rowK1[dc * 32 + h * 8 + 4];
        }

        float vv[8][8];
        #pragma unroll
        for (int e = 0; e < 8; ++e) {
            const int p = h * 8 + e;
            const int s = s0 + p;
            const float* rowV = (s == len - 1) ? &vnew[nbase]
                : &vcache[(((size_t)(p < 16 ? blk0 : blk1) * 16 + (p & 15)) * 2 + kh) * 128];
            #pragma unroll
            for (int dt = 0; dt < 8; ++dt)
                vv[e][dt] = rowV[dt * 16 + g];
        }

        f32x4 sa0 = (f32x4){0.f,0.f,0.f,0.f};
        f32x4 sa1 = (f32x4){0.f,0.f,0.f,0.f};
        #pragma unroll
        for (int dc = 0; dc < 4; ++dc) {
            bh8 a0, a1;
            a0[0]=f2bf(k0[2*dc].x);   a0[1]=f2bf(k0[2*dc].y);
            a0[2]=f2bf(k0[2*dc].z);   a0[3]=f2bf(k0[2*dc].w);
            a0[4]=f2bf(k0[2*dc+1].x); a0[5]=f2bf(k0[2*dc+1].y);
            a0[6]=f2bf(k0[2*dc+1].z); a0[7]=f2bf(k0[2*dc+1].w);
            a1[0]=f2bf(k1[2*dc].x);   a1[1]=f2bf(k1[2*dc].y);
            a1[2]=f2bf(k1[2*dc].z);   a1[3]=f2bf(k1[2*dc].w);
            a1[4]=f2bf(k1[2*dc+1].x); a1[5]=f2bf(k1[2*dc+1].y);
            a1[6]=f2bf(k1[2*dc+1].z); a1[7]=f2bf(k1[2*dc+1].w);
            sa0 = __builtin_amdgcn_mfma_f32_16x16x32_bf16(a0, qf[dc], sa0, 0, 0, 0);
            sa1 = __builtin_amdgcn_mfma_f32_16x16x32_bf16(a1, qf[dc], sa1, 0, 0, 0);
        }

        float sc[8];
        #pragma unroll
        for (int j = 0; j < 4; ++j) {
            sc[j]     = (s0 + 4*h + j      < len) ? sa0[j] : -INFINITY;
            sc[4 + j] = (s0 + 16 + 4*h + j < len) ? sa1[j] : -INFINITY;
        }
        float tmax = sc[0];
        #pragma unroll
        for (int j = 1; j < 8; ++j) tmax = fmaxf(tmax, sc[j]);
        tmax = fmaxf(tmax, __shfl_xor(tmax, 16));
        tmax = fmaxf(tmax, __shfl_xor(tmax, 32));
        const float m_new = fmaxf(m, tmax);
        const float corr = expf(m - m_new);
        float pe[8], ls = 0.f;
        #pragma unroll
        for (int j = 0; j < 8; ++j) { pe[j] = expf(sc[j] - m_new); ls += pe[j]; }
        ls += __shfl_xor(ls, 16);
        ls += __shfl_xor(ls, 32);
        lacc = lacc * corr + ls;
        m = m_new;
        #pragma unroll
        for (int dt = 0; dt < 8; ++dt) {
            oacc[dt][0] *= corr; oacc[dt][1] *= corr;
            oacc[dt][2] *= corr; oacc[dt][3] *= corr;
        }

        unsigned int* myP = sP[wv];
        #pragma unroll
        for (int ph = 0; ph < 2; ++ph)
            #pragma unroll
            for (int t2 = 0; t2 < 2; ++t2) {
                unsigned lo = (unsigned short)f2bf(pe[ph*4 + 2*t2]);
                unsigned hi = (unsigned short)f2bf(pe[ph*4 + 2*t2 + 1]);
                myP[g * 16 + ph * 8 + 2 * h + t2] = lo | (hi << 16);
            }
        asm volatile("s_waitcnt lgkmcnt(0)" ::: "memory");
        bh8 pf = *(const bh8*)&myP[g * 16 + 4 * h];

        #pragma unroll
        for (int dt = 0; dt < 8; ++dt) {
            bh8 av;
            #pragma unroll
            for (int e = 0; e < 8; ++e) av[e] = f2bf(vv[e][dt]);
            oacc[dt] = __builtin_amdgcn_mfma_f32_16x16x32_bf16(av, pf, oacc[dt], 0, 0, 0);
        }
    }

    if (wv > 0) {
        #pragma unroll
        for (int dt = 0; dt < 8; ++dt)
            #pragma unroll
            for (int j = 0; j < 4; ++j)
                sO[wv-1][g][dt*16 + 4*h + j] = oacc[dt][j];
        if (l < 16) {
            sML[wv-1][0][g] = m;
            sML[wv-1][1][g] = lacc;
        }
    }
    __syncthreads();
    if (wv == 0) {
        float M = m;
        #pragma unroll
        for (int i = 0; i < 3; ++i) M = fmaxf(M, sML[i][0][g]);
        const float w0 = expf(m - M);
        float L = lacc * w0;
        float wi[3];
        #pragma unroll
        for (int i = 0; i < 3; ++i) {
            wi[i] = expf(sML[i][0][g] - M);
            L += sML[i][1][g] * wi[i];
        }
        size_t base = ((((size_t)(b * 2 + kh)) * SPLITS + split) * 16 + g) * 128;
        #pragma unroll
        for (int dt = 0; dt < 8; ++dt)
            #pragma unroll
            for (int j = 0; j < 4; ++j) {
                float o = oacc[dt][j] * w0;
                #pragma unroll
                for (int i = 0; i < 3; ++i)
                    o += sO[i][g][dt*16 + 4*h + j] * wi[i];
                pO[base + dt*16 + 4*h + j] = o;
            }
        if (l < 16) {
            size_t mb = ((((size_t)(b * 2 + kh)) * SPLITS + split) * 16 + g) * 2;
            pML[mb] = M;
            pML[mb + 1] = L;
        }
    }
}

// Combine splits AND emit dense-GEMM input pre-split to bf16 hi/lo.
__global__ __launch_bounds__(256) void attn_combine(
    const float* __restrict__ pO, const float* __restrict__ pML,
    unsigned short* __restrict__ a_hi, unsigned short* __restrict__ a_lo)
{
    const int bk = blockIdx.x;
    const int tid = threadIdx.x;
    const int g = tid >> 4;
    const int dh = tid & 15;

    float ms[SPLITS], ls[SPLITS];
    float M = -INFINITY;
    #pragma unroll
    for (int s = 0; s < SPLITS; ++s) {
        size_t mb = (((size_t)bk * SPLITS + s) * 16 + g) * 2;
        ms[s] = pML[mb]; ls[s] = pML[mb + 1];
        M = fmaxf(M, ms[s]);
    }
    float L = 0.f;
    #pragma unroll
    for (int s = 0; s < SPLITS; ++s) L += ls[s] * expf(ms[s] - M);

    float acc[8] = {0, 0, 0, 0, 0, 0, 0, 0};
    #pragma unroll
    for (int s = 0; s < SPLITS; ++s) {
        float wgt = expf(ms[s] - M);
        const float* src = &pO[(((size_t)bk * SPLITS + s) * 16 + g) * 128 + dh * 8];
        #pragma unroll
        for (int r = 0; r < 8; ++r) acc[r] += wgt * src[r];
    }
    const float invL = 1.f / L;
    const int b = bk >> 1, kh = bk & 1;
    const size_t idx = (size_t)b * 4096 + (kh * 16 + g) * 128 + dh * 8;
    unsigned short hbuf[8], lbuf[8];
    #pragma unroll
    for (int r = 0; r < 8; ++r) {
        float o = acc[r] * invL;
        short hh = f2bf(o);
        hbuf[r] = (unsigned short)hh;
        lbuf[r] = (unsigned short)f2bf(o - bf2f(hh));
    }
    *(int4*)&a_hi[idx] = *(int4*)hbuf;
    *(int4*)&a_lo[idx] = *(int4*)lbuf;
}

__global__ __launch_bounds__(256) void reduce_dense(
    const float* __restrict__ part, float* __restrict__ out)
{
    const int b = blockIdx.y;
    const int col = (blockIdx.x * 256 + threadIdx.x) * 4;
    float4 s = make_float4(0.f, 0.f, 0.f, 0.f);
    #pragma unroll
    for (int ks = 0; ks < KSPLIT; ++ks) {
        float4 v = *(const float4*)&part[((size_t)ks * 64 + b) * NDENSE + col];
        s.x += v.x; s.y += v.y; s.z += v.z; s.w += v.w;
    }
    *(float4*)&out[(size_t)b * 4096 + col] = s;
}

extern "C" void kernel_launch(void* const* d_in, const int* in_sizes, int n_in,
                              void* d_out, int out_size, void* d_ws, size_t ws_size,
                              hipStream_t stream) {
    const float* hidden = (const float*)d_in[0];
    const float* wqkv   = (const float*)d_in[1];
    const float* wdense = (const float*)d_in[2];
    const float* kcache = (const float*)d_in[3];
    const float* vcache = (const float*)d_in[4];
    const int*   bt     = (const int*)d_in[5];
    const int*   lens   = (const int*)d_in[7];
    float* out = (float*)d_out;

    float* ws     = (float*)d_ws;
    float* q_rope = ws;                       // 262144 f
    float* k_new  = ws + 262144;              // 16384 f
    float* v_new  = ws + 278528;              // 16384 f
    unsigned short* hiloA = (unsigned short*)(ws + 294912);  // 262144 f region
    unsigned short* A_hi = hiloA;             // 262144 ushort
    unsigned short* A_lo = hiloA + 262144;    // 262144 ushort
    float* regX   = ws + 557056;              // 2359296 f (partials / pO)
    float* pO     = regX;
    float* pML    = ws + 2916352;             // 32768 f
    // total: 2949120 floats = 11.80 MB

    prep_hilo<<<dim3(256), dim3(256), 0, stream>>>(hidden, A_hi, A_lo);
    gemm_mfma<<<dim3(NQKV / 64, KSPLIT), dim3(256), 0, stream>>>(
        A_hi, A_lo, wqkv, regX, NQKV);
    reduce_qkv<<<dim3(9, 64), dim3(256), 0, stream>>>(
        regX, lens, q_rope, k_new, v_new);
    attn_mfma<<<dim3(SPLITS, 2, 64), dim3(256), 0, stream>>>(
        q_rope, k_new, v_new, kcache, vcache, bt, lens, pO, pML);
    attn_combine<<<dim3(128), dim3(256), 0, stream>>>(pO, pML, A_hi, A_lo);
    gemm_mfma<<<dim3(NDENSE / 64, KSPLIT), dim3(256), 0, stream>>>(
        A_hi, A_lo, wdense, regX, NDENSE);
    reduce_dense<<<dim3(4, 64), dim3(256), 0, stream>>>(regX, out);
}